// Round 1
// baseline (253.905 us; speedup 1.0000x reference)
//
#include <hip/hip_runtime.h>

// Sparse submanifold 3D conv, f32.
// out[n,co] = bias[co] + sum_k sum_ci feats[nbr[n,k],ci] * W[k,ci,co]
// Layout: one wave (64 lanes) per 64 output rows; lane = co (C_OUT==64).
// k outer: W[k][:,lane] register-cached (32 VGPR), amortized over 64 rows.
// ~90% of (n,k) pairs are sentinel -> skipped via wave-uniform scalar branches
// on a __ballot mask (no divergence, acc[] statically indexed).

constexpr int C_IN_  = 32;
constexpr int C_OUT_ = 64;
constexpr int KVOL_  = 27;
constexpr int RPW    = 64;   // rows per wave (1 wave per block)

__global__ __launch_bounds__(64, 4)
void spconv_f32_kernel(const float* __restrict__ features,
                       const float* __restrict__ weight,
                       const float* __restrict__ bias,
                       const int*   __restrict__ nbr,
                       float*       __restrict__ out,
                       int n)
{
    const int lane = threadIdx.x;        // 0..63 == output channel
    const int r0   = blockIdx.x * RPW;   // first output row of this wave

    // accumulators: acc[r] = out[r0+r, lane]
    float acc[RPW];
    const float b = bias[lane];
#pragma unroll
    for (int r = 0; r < RPW; ++r) acc[r] = b;

    const int  myrow = r0 + lane;
    const bool rowok = (myrow < n);

#pragma unroll 1
    for (int k = 0; k < KVOL_; ++k) {
        // Register-cache W[k][ci][lane]: 32 coalesced 256B loads, amortized
        // over the 64 rows of this wave.
        float w[C_IN_];
        const float* wk = weight + (size_t)k * (C_IN_ * C_OUT_) + lane;
#pragma unroll
        for (int ci = 0; ci < C_IN_; ++ci) w[ci] = wk[(size_t)ci * C_OUT_];

        // lane r fetches the neighbor index for row r0+r at offset k
        int idxv = rowok ? nbr[(size_t)myrow * KVOL_ + k] : n;
        const unsigned long long mask = __ballot(idxv != n);

        // Fully unrolled row loop: constant bit-test -> uniform scalar branch.
        // acc[] indexing stays compile-time constant (no scratch).
#pragma unroll
        for (int r = 0; r < RPW; ++r) {
            if (mask & (1ull << r)) {
                const int idx = __builtin_amdgcn_readlane(idxv, r); // uniform
                const float* frow = features + (size_t)idx * C_IN_;
#pragma unroll
                for (int ci = 0; ci < C_IN_; ++ci)
                    acc[r] = fmaf(frow[ci], w[ci], acc[r]);
            }
        }
    }

    // Coalesced store: 256B per row
#pragma unroll
    for (int r = 0; r < RPW; ++r) {
        if (r0 + r < n)
            out[(size_t)(r0 + r) * C_OUT_ + lane] = acc[r];
    }
}

extern "C" void kernel_launch(void* const* d_in, const int* in_sizes, int n_in,
                              void* d_out, int out_size, void* d_ws, size_t ws_size,
                              hipStream_t stream)
{
    const float* features = (const float*)d_in[0];   // (N, 32) f32
    const float* weight   = (const float*)d_in[1];   // (27, 32, 64) f32
    const float* bias     = (const float*)d_in[2];   // (64,) f32
    const int*   nbr      = (const int*)  d_in[3];   // (N, 27) i32, sentinel = N

    float* out = (float*)d_out;                      // (N, 64) f32

    const int n    = in_sizes[0] / C_IN_;
    const int grid = (n + RPW - 1) / RPW;

    spconv_f32_kernel<<<dim3(grid), dim3(64), 0, stream>>>(
        features, weight, bias, nbr, out, n);
}

// Round 2
// 174.012 us; speedup vs baseline: 1.4591x; 1.4591x over previous
//
#include <hip/hip_runtime.h>

// Sparse submanifold 3D conv, f32.
// out[n,co] = bias[co] + sum_k sum_ci feats[nbr[n,k],ci] * W[k,ci,co]
// One wave (64 lanes) per 32 output rows; lane = co (C_OUT==64).
// Round-1 fix: RPW 64->32 so acc[]+w[] fit in VGPRs (R0 spilled: VGPR=52
// for 96+ live floats). Block 256 (4 independent waves) for occupancy.

constexpr int C_IN_  = 32;
constexpr int C_OUT_ = 64;
constexpr int KVOL_  = 27;
constexpr int RPW    = 32;   // rows per wave
constexpr int WPB    = 4;    // waves per block

__global__ __launch_bounds__(256, 4)
void spconv_f32_kernel(const float* __restrict__ features,
                       const float* __restrict__ weight,
                       const float* __restrict__ bias,
                       const int*   __restrict__ nbr,
                       float*       __restrict__ out,
                       int n)
{
    const int lane = threadIdx.x & 63;          // 0..63 == output channel
    const int wid  = threadIdx.x >> 6;          // wave id in block
    const int wave = blockIdx.x * WPB + wid;    // global wave id
    const int r0   = wave * RPW;                // first output row
    if (r0 >= n) return;                        // wave-uniform, no sync used

    // accumulators: acc[r] = out[r0+r, lane]
    float acc[RPW];
    const float b = bias[lane];
#pragma unroll
    for (int r = 0; r < RPW; ++r) acc[r] = b;

    const int  myrow = r0 + lane;                       // row probed by this lane
    const bool rowok = (lane < RPW) && (myrow < n);     // lanes 32..63 idle here

#pragma unroll 1
    for (int k = 0; k < KVOL_; ++k) {
        // Register-cache W[k][ci][lane]: 32 coalesced 256B loads,
        // amortized over the 32 rows of this wave.
        float w[C_IN_];
        const float* wk = weight + (size_t)k * (C_IN_ * C_OUT_) + lane;
#pragma unroll
        for (int ci = 0; ci < C_IN_; ++ci) w[ci] = wk[(size_t)ci * C_OUT_];

        // lane r (r<32) fetches the neighbor index for row r0+r at offset k
        int idxv = rowok ? nbr[(size_t)myrow * KVOL_ + k] : n;
        const unsigned long long mask = __ballot(idxv != n);  // bits 0..31 only

        // Fully unrolled row loop: constant bit-test -> uniform scalar branch.
        // acc[] indexing stays compile-time constant (no scratch).
#pragma unroll
        for (int r = 0; r < RPW; ++r) {
            if (mask & (1ull << r)) {
                const int idx = __builtin_amdgcn_readlane(idxv, r); // uniform SGPR
                const float* frow = features + (size_t)idx * C_IN_;
#pragma unroll
                for (int ci = 0; ci < C_IN_; ++ci)
                    acc[r] = fmaf(frow[ci], w[ci], acc[r]);
            }
        }
    }

    // Coalesced store: 256B per row
#pragma unroll
    for (int r = 0; r < RPW; ++r) {
        if (r0 + r < n)
            out[(size_t)(r0 + r) * C_OUT_ + lane] = acc[r];
    }
}

extern "C" void kernel_launch(void* const* d_in, const int* in_sizes, int n_in,
                              void* d_out, int out_size, void* d_ws, size_t ws_size,
                              hipStream_t stream)
{
    const float* features = (const float*)d_in[0];   // (N, 32) f32
    const float* weight   = (const float*)d_in[1];   // (27, 32, 64) f32
    const float* bias     = (const float*)d_in[2];   // (64,) f32
    const int*   nbr      = (const int*)  d_in[3];   // (N, 27) i32, sentinel = N

    float* out = (float*)d_out;                      // (N, 64) f32

    const int n     = in_sizes[0] / C_IN_;
    const int waves = (n + RPW - 1) / RPW;
    const int grid  = (waves + WPB - 1) / WPB;

    spconv_f32_kernel<<<dim3(grid), dim3(256), 0, stream>>>(
        features, weight, bias, nbr, out, n);
}